// Round 18
// baseline (320.076 us; speedup 1.0000x reference)
//
#include <hip/hip_runtime.h>

#define B_ 512
#define T_ 512
#define V_ 96
#define H_ 128
#define K2F 2.8853900817779268f   // 2*log2(e): exp(2s) == exp2(K2F*s)

typedef _Float16 half8 __attribute__((ext_vector_type(8)));
typedef float    f32x4 __attribute__((ext_vector_type(4)));

// Pass 1a: recover the one-hot index per (b,t). x is exactly {0.0, 1.0}.
__global__ __launch_bounds__(256) void onehot_idx_kernel(
    const float4* __restrict__ x4, int n4, int* __restrict__ idx)
{
    int stride = gridDim.x * blockDim.x;
    for (int e4 = blockIdx.x * blockDim.x + threadIdx.x; e4 < n4; e4 += stride) {
        float4 v = x4[e4];
        int base = e4 * 4;
        if (v.x > 0.5f) idx[(base + 0) / V_] = (base + 0) % V_;
        if (v.y > 0.5f) idx[(base + 1) / V_] = (base + 1) % V_;
        if (v.z > 0.5f) idx[(base + 2) / V_] = (base + 2) % V_;
        if (v.w > 0.5f) idx[(base + 3) / V_] = (base + 3) % V_;
    }
}

// Pass 1b (R16-VERIFIED): xwg[v][u'] with u' = (u&15)*8 + (u>>4); a lane's
// per-row xw pair for n-tiles {2ww, 2ww+1} is one aligned float2.
__global__ __launch_bounds__(256) void build_xwg_kernel(
    const float* __restrict__ W_ih, const float* __restrict__ b_ih,
    const float* __restrict__ b_hh, float* __restrict__ xwg)
{
    int e = blockIdx.x * 256 + threadIdx.x;
    if (e < V_ * H_) {
        int v = e >> 7, up = e & 127;
        int u = (up & 7) * 16 + (up >> 3);
        xwg[e] = (W_ih[u * V_ + v] + b_ih[u] + b_hh[u]) * K2F;
    }
}

// Pass 1c (R16-VERIFIED): recurrence B-frags, K2F pre-scaled f16.
__global__ __launch_bounds__(256) void build_wB_kernel(
    const float* __restrict__ W_hh, _Float16* __restrict__ wB)
{
    int e = blockIdx.x * 256 + threadIdx.x;     // 4ks*8nt*64lane*8reg = 16384
    if (e < 16384) {
        int reg = e & 7, lane = (e >> 3) & 63, nt = (e >> 9) & 7, ks = e >> 12;
        int unit = ks * 32 + (lane >> 4) * 8 + reg;
        int n    = nt * 16 + (lane & 15);
        wB[e] = (_Float16)(K2F * W_hh[n * H_ + unit]);
    }
}

// Pass 1d (R16-VERIFIED): fc B-frags (unscaled W_fc, f16), 6 n-tiles.
__global__ __launch_bounds__(256) void build_wBfc_kernel(
    const float* __restrict__ W_fc, _Float16* __restrict__ wBfc)
{
    int e = blockIdx.x * 256 + threadIdx.x;     // 4*6*64*8 = 12288
    if (e < 12288) {
        int reg = e & 7, lane = (e >> 3) & 63;
        int nt = (e >> 9) % 6, ks = e / 3072;
        int unit = ks * 32 + (lane >> 4) * 8 + reg;
        int n    = nt * 16 + (lane & 15);
        wBfc[e] = (_Float16)W_fc[n * H_ + unit];
    }
}

// Pass 2: 8 waves / block, TWO independent 16-row groups (32 rows/block,
// grid=16). Wave w: group grp = w>>2, n-tiles {2ww, 2ww+1} with ww = w&3.
// Each SIMD hosts 2 waves from DIFFERENT groups -> one group's ds_read /
// MFMA / trans latency is filled by the other group's issue (R17 was 1
// wave/SIMD and ~70% latency-stall). MFMA accum chain split 2+2 to halve
// its serial latency. Same verified math as R16/R17.
__global__ __launch_bounds__(512, 1) void rnn_mfma8_kernel(
    const uint4* __restrict__ wBg, const uint4* __restrict__ wBfcg,
    const float* __restrict__ xwg, const int* __restrict__ idx,
    const float* __restrict__ b_fc, float* __restrict__ out)
{
    const int bb  = blockIdx.x;        // rows 32*bb .. 32*bb+31
    const int tid = threadIdx.x;
    const int w   = tid >> 6;          // wave 0..7
    const int grp = w >> 2;            // row-group 0/1
    const int ww  = w & 3;             // n-tile pair {2ww, 2ww+1}
    const int l   = tid & 63;
    const int lo  = l & 15, g = l >> 4;
    const int rowbase = bb * 32 + grp * 16;

    __shared__ _Float16      hs[2][2][16][136];      // [grp][buf][row][unit]
    __shared__ unsigned char idxT[2][(T_ + 2) * 16]; // [grp][t][row]

    for (int e = tid; e < 32 * T_; e += 512) {
        int row = e >> 9, t = e & 511;
        idxT[row >> 4][t * 16 + (row & 15)] =
            (unsigned char)idx[(bb * 32 + row) * T_ + t];
    }
    if (tid < 64) idxT[tid >> 5][T_ * 16 + (tid & 31)] = 0;  // t+2 lookahead pad
    for (int e = tid; e < 2 * 16 * 136; e += 512) {
        int gz = e / 2176, rem = e % 2176;
        hs[gz][0][rem / 136][rem % 136] = (_Float16)0.f;
    }

    // this wave's B-frags: 8 x uint4 = 32 regs, loaded ONCE
    uint4 wb[4][2];
    #pragma unroll
    for (int ks = 0; ks < 4; ++ks)
        #pragma unroll
        for (int q = 0; q < 2; ++q)
            wb[ks][q] = wBg[(ks * 8 + 2 * ww + q) * 64 + l];

    // prologue: xw for t=0 (float2 per row), ids for t=1
    float2 xwc[4];
    unsigned idw;
    __builtin_memcpy(&idw, &idxT[grp][0 * 16 + 4 * g], 4);
    #pragma unroll
    for (int j = 0; j < 4; ++j) {
        int id = (idw >> (8 * j)) & 255;
        xwc[j] = *(const float2*)(xwg + id * 128 + lo * 8 + 2 * ww);
    }
    __builtin_memcpy(&idw, &idxT[grp][1 * 16 + 4 * g], 4);

    __syncthreads();

    int cur = 0;
    #pragma clang loop unroll(disable)
    for (int t = 0; t < T_; ++t) {
        // A-frags: h_{t-1} row-major (memcpy: may-alias, RAW modeled)
        half8 aF[4];
        #pragma unroll
        for (int ks = 0; ks < 4; ++ks)
            __builtin_memcpy(&aF[ks], &hs[grp][cur][lo][ks * 32 + g * 8], 16);

        // prefetch next step's xw (global float2 x4, ~1.5 steps of slack)
        float2 xwn[4];
        #pragma unroll
        for (int j = 0; j < 4; ++j) {
            int id = (idw >> (8 * j)) & 255;
            xwn[j] = *(const float2*)(xwg + id * 128 + lo * 8 + 2 * ww);
        }
        __builtin_memcpy(&idw, &idxT[grp][(t + 2) * 16 + 4 * g], 4);

        // 8 MFMAs, 2+2 split chains: halves the serial MFMA latency
        f32x4 p0 = {0.f,0.f,0.f,0.f}, p1 = {0.f,0.f,0.f,0.f};
        f32x4 q0 = {0.f,0.f,0.f,0.f}, q1 = {0.f,0.f,0.f,0.f};
        #pragma unroll
        for (int ks = 0; ks < 2; ++ks) {
            union { uint4 u; half8 h; } u0, u1, u2, u3;
            u0.u = wb[ks][0];     u1.u = wb[ks][1];
            u2.u = wb[ks + 2][0]; u3.u = wb[ks + 2][1];
            p0 = __builtin_amdgcn_mfma_f32_16x16x32_f16(aF[ks],     u0.h, p0, 0, 0, 0);
            p1 = __builtin_amdgcn_mfma_f32_16x16x32_f16(aF[ks],     u1.h, p1, 0, 0, 0);
            q0 = __builtin_amdgcn_mfma_f32_16x16x32_f16(aF[ks + 2], u2.h, q0, 0, 0, 0);
            q1 = __builtin_amdgcn_mfma_f32_16x16x32_f16(aF[ks + 2], u3.h, q1, 0, 0, 0);
        }
        f32x4 acc0 = p0 + q0, acc1 = p1 + q1;

        // tail: tanh(s) = 1 - 2/(exp2(acc + xw) + 1); 8 values/lane
        #pragma unroll
        for (int j = 0; j < 4; ++j) {
            float E0 = __builtin_amdgcn_exp2f(acc0[j] + xwc[j].x);
            float E1 = __builtin_amdgcn_exp2f(acc1[j] + xwc[j].y);
            float h0 = 1.0f - 2.0f * __builtin_amdgcn_rcpf(E0 + 1.0f);
            float h1 = 1.0f - 2.0f * __builtin_amdgcn_rcpf(E1 + 1.0f);
            hs[grp][cur ^ 1][4 * g + j][(2 * ww + 0) * 16 + lo] = (_Float16)h0;
            hs[grp][cur ^ 1][4 * g + j][(2 * ww + 1) * 16 + lo] = (_Float16)h1;
        }
        #pragma unroll
        for (int j = 0; j < 4; ++j) xwc[j] = xwn[j];
        cur ^= 1;
        __syncthreads();                       // h complete before next A-read
    }

    // fc epilogue: wave w does vocab tiles {2ww, 2ww+1} below V_=96 (6 tiles)
    half8 aE[4];
    #pragma unroll
    for (int ks = 0; ks < 4; ++ks)
        __builtin_memcpy(&aE[ks], &hs[grp][cur][lo][ks * 32 + g * 8], 16);
    #pragma unroll
    for (int q = 0; q < 2; ++q) {
        const int NT = 2 * ww + q;
        if (NT < 6) {
            float bf = b_fc[NT * 16 + lo];
            f32x4 acc = {bf, bf, bf, bf};
            #pragma unroll
            for (int ks = 0; ks < 4; ++ks) {
                union { uint4 u; half8 h; } ub;
                ub.u = wBfcg[(ks * 6 + NT) * 64 + l];
                acc = __builtin_amdgcn_mfma_f32_16x16x32_f16(aE[ks], ub.h, acc, 0, 0, 0);
            }
            #pragma unroll
            for (int j = 0; j < 4; ++j)
                out[(rowbase + 4 * g + j) * V_ + NT * 16 + lo] = acc[j];
        }
    }
}

extern "C" void kernel_launch(void* const* d_in, const int* in_sizes, int n_in,
                              void* d_out, int out_size, void* d_ws, size_t ws_size,
                              hipStream_t stream)
{
    const float* x    = (const float*)d_in[0];
    const float* W_ih = (const float*)d_in[1];
    const float* b_ih = (const float*)d_in[2];
    const float* W_hh = (const float*)d_in[3];
    const float* b_hh = (const float*)d_in[4];
    const float* W_fc = (const float*)d_in[5];
    const float* b_fc = (const float*)d_in[6];
    float* out = (float*)d_out;

    char* ws = (char*)d_ws;
    int*      idx  = (int*)ws;                               // 1 MiB
    float*    xwg  = (float*)(ws + (size_t)B_ * T_ * 4);     // 48 KiB
    _Float16* wB   = (_Float16*)((char*)xwg + V_ * H_ * 4);  // 32 KiB
    _Float16* wBfc = (_Float16*)((char*)wB + 16384 * 2);     // 24 KiB

    const int n4 = (B_ * T_ * V_) / 4;
    hipLaunchKernelGGL(onehot_idx_kernel, dim3(2048), dim3(256), 0, stream,
                       (const float4*)x, n4, idx);
    hipLaunchKernelGGL(build_xwg_kernel, dim3((V_ * H_ + 255) / 256), dim3(256),
                       0, stream, W_ih, b_ih, b_hh, xwg);
    hipLaunchKernelGGL(build_wB_kernel, dim3(64), dim3(256), 0, stream, W_hh, wB);
    hipLaunchKernelGGL(build_wBfc_kernel, dim3(48), dim3(256), 0, stream, W_fc, wBfc);
    hipLaunchKernelGGL(rnn_mfma8_kernel, dim3(B_ / 32), dim3(512), 0, stream,
                       (const uint4*)wB, (const uint4*)wBfc, xwg, idx, b_fc, out);
}

// Round 19
// 224.916 us; speedup vs baseline: 1.4231x; 1.4231x over previous
//
#include <hip/hip_runtime.h>

#define B_ 512
#define T_ 512
#define V_ 96
#define H_ 128
#define XST 132   // xwl row stride (floats): banks shift 4*id -> gather spread
#define K2F 2.8853900817779268f   // 2*log2(e): exp(2s) == exp2(K2F*s)

typedef _Float16 half8 __attribute__((ext_vector_type(8)));
typedef float    f32x4 __attribute__((ext_vector_type(4)));

// Pass 1a: recover the one-hot index per (b,t). x is exactly {0.0, 1.0}.
__global__ __launch_bounds__(256) void onehot_idx_kernel(
    const float4* __restrict__ x4, int n4, int* __restrict__ idx)
{
    int stride = gridDim.x * blockDim.x;
    for (int e4 = blockIdx.x * blockDim.x + threadIdx.x; e4 < n4; e4 += stride) {
        float4 v = x4[e4];
        int base = e4 * 4;
        if (v.x > 0.5f) idx[(base + 0) / V_] = (base + 0) % V_;
        if (v.y > 0.5f) idx[(base + 1) / V_] = (base + 1) % V_;
        if (v.z > 0.5f) idx[(base + 2) / V_] = (base + 2) % V_;
        if (v.w > 0.5f) idx[(base + 3) / V_] = (base + 3) % V_;
    }
}

// Pass 1b (R16-VERIFIED): xwg[v][u'] with u' = (u&15)*8 + (u>>4); a lane's
// per-row xw pair for n-tiles {2w, 2w+1} is one aligned float2.
__global__ __launch_bounds__(256) void build_xwg_kernel(
    const float* __restrict__ W_ih, const float* __restrict__ b_ih,
    const float* __restrict__ b_hh, float* __restrict__ xwg)
{
    int e = blockIdx.x * 256 + threadIdx.x;
    if (e < V_ * H_) {
        int v = e >> 7, up = e & 127;
        int u = (up & 7) * 16 + (up >> 3);
        xwg[e] = (W_ih[u * V_ + v] + b_ih[u] + b_hh[u]) * K2F;
    }
}

// Pass 1c (R16-VERIFIED): recurrence B-frags, K2F pre-scaled f16.
__global__ __launch_bounds__(256) void build_wB_kernel(
    const float* __restrict__ W_hh, _Float16* __restrict__ wB)
{
    int e = blockIdx.x * 256 + threadIdx.x;     // 4ks*8nt*64lane*8reg = 16384
    if (e < 16384) {
        int reg = e & 7, lane = (e >> 3) & 63, nt = (e >> 9) & 7, ks = e >> 12;
        int unit = ks * 32 + (lane >> 4) * 8 + reg;
        int n    = nt * 16 + (lane & 15);
        wB[e] = (_Float16)(K2F * W_hh[n * H_ + unit]);
    }
}

// Pass 1d (R16-VERIFIED): fc B-frags (unscaled W_fc, f16), 6 n-tiles.
__global__ __launch_bounds__(256) void build_wBfc_kernel(
    const float* __restrict__ W_fc, _Float16* __restrict__ wBfc)
{
    int e = blockIdx.x * 256 + threadIdx.x;     // 4*6*64*8 = 12288
    if (e < 12288) {
        int reg = e & 7, lane = (e >> 3) & 63;
        int nt = (e >> 9) % 6, ks = e / 3072;
        int unit = ks * 32 + (lane >> 4) * 8 + reg;
        int n    = nt * 16 + (lane & 15);
        wBfc[e] = (_Float16)W_fc[n * H_ + unit];
    }
}

// Pass 2: 4 waves / 16 rows / block, grid=32 (R17 base) with ZERO vmem in
// the step loop. R17 kept global xw loads inside the barriered loop:
// __syncthreads == s_waitcnt vmcnt(0) + s_barrier, so every step paid an
// L2 round-trip at the barrier (the R4->R5 lesson, re-violated). The xw
// table now lives in LDS (50.7 KiB, stride 132: gather banks shift by
// 4*id); the whole loop is lgkm-only. MFMA chain split 2+2 (R18).
__global__ __launch_bounds__(256, 1) void rnn_mfma4_kernel(
    const uint4* __restrict__ wBg, const uint4* __restrict__ wBfcg,
    const float* __restrict__ xwg, const int* __restrict__ idx,
    const float* __restrict__ b_fc, float* __restrict__ out)
{
    const int bb  = blockIdx.x;        // rows 16*bb .. 16*bb+15
    const int tid = threadIdx.x;
    const int w   = tid >> 6;          // wave 0..3 -> n-tiles {2w, 2w+1}
    const int l   = tid & 63;
    const int lo  = l & 15, g = l >> 4;

    __shared__ float         xwl[V_ * XST];       // 50.7 KiB LDS gather table
    __shared__ _Float16      hs[2][16][136];      // dbl-buffered h, +8 pad
    __shared__ unsigned char idxT[T_ * 16];       // [t][row] char ids

    for (int e = tid; e < V_ * H_; e += 256) {
        int v = e >> 7, up = e & 127;
        xwl[v * XST + up] = xwg[e];
    }
    for (int e = tid; e < 16 * T_; e += 256) {
        int row = e >> 9, t = e & 511;
        idxT[t * 16 + row] = (unsigned char)idx[(bb * 16 + row) * T_ + t];
    }
    for (int e = tid; e < 16 * 136; e += 256)
        hs[0][e / 136][e % 136] = (_Float16)0.f;

    // this wave's B-frags: 8 x uint4 = 32 regs, loaded ONCE
    uint4 wb[4][2];
    #pragma unroll
    for (int ks = 0; ks < 4; ++ks)
        #pragma unroll
        for (int q = 0; q < 2; ++q)
            wb[ks][q] = wBg[(ks * 8 + 2 * w + q) * 64 + l];

    __syncthreads();

    int cur = 0;
    #pragma clang loop unroll(disable)
    for (int t = 0; t < T_; ++t) {
        // char ids for this step (LDS broadcast, 4B per g-group)
        unsigned idw;
        __builtin_memcpy(&idw, &idxT[t * 16 + 4 * g], 4);

        // A-frags: h_{t-1} row-major (memcpy: may-alias, RAW modeled)
        half8 aF[4];
        #pragma unroll
        for (int ks = 0; ks < 4; ++ks)
            __builtin_memcpy(&aF[ks], &hs[cur][lo][ks * 32 + g * 8], 16);

        // xw gather from LDS (ds_read_b64 x4; consumed only in the tail,
        // ~300 cy later -- latency hidden under the MFMA chain)
        float2 xwc[4];
        #pragma unroll
        for (int j = 0; j < 4; ++j) {
            int id = (idw >> (8 * j)) & 255;
            __builtin_memcpy(&xwc[j], &xwl[id * XST + lo * 8 + 2 * w], 8);
        }

        // 8 MFMAs, 2+2 split chains (halves serial MFMA latency)
        f32x4 p0 = {0.f,0.f,0.f,0.f}, p1 = {0.f,0.f,0.f,0.f};
        f32x4 q0 = {0.f,0.f,0.f,0.f}, q1 = {0.f,0.f,0.f,0.f};
        #pragma unroll
        for (int ks = 0; ks < 2; ++ks) {
            union { uint4 u; half8 h; } u0, u1, u2, u3;
            u0.u = wb[ks][0];     u1.u = wb[ks][1];
            u2.u = wb[ks + 2][0]; u3.u = wb[ks + 2][1];
            p0 = __builtin_amdgcn_mfma_f32_16x16x32_f16(aF[ks],     u0.h, p0, 0, 0, 0);
            p1 = __builtin_amdgcn_mfma_f32_16x16x32_f16(aF[ks],     u1.h, p1, 0, 0, 0);
            q0 = __builtin_amdgcn_mfma_f32_16x16x32_f16(aF[ks + 2], u2.h, q0, 0, 0, 0);
            q1 = __builtin_amdgcn_mfma_f32_16x16x32_f16(aF[ks + 2], u3.h, q1, 0, 0, 0);
        }
        f32x4 acc0 = p0 + q0, acc1 = p1 + q1;

        // tail: tanh(s) = 1 - 2/(exp2(acc + xw) + 1); 8 values/lane
        #pragma unroll
        for (int j = 0; j < 4; ++j) {
            float E0 = __builtin_amdgcn_exp2f(acc0[j] + xwc[j].x);
            float E1 = __builtin_amdgcn_exp2f(acc1[j] + xwc[j].y);
            float h0 = 1.0f - 2.0f * __builtin_amdgcn_rcpf(E0 + 1.0f);
            float h1 = 1.0f - 2.0f * __builtin_amdgcn_rcpf(E1 + 1.0f);
            hs[cur ^ 1][4 * g + j][(2 * w + 0) * 16 + lo] = (_Float16)h0;
            hs[cur ^ 1][4 * g + j][(2 * w + 1) * 16 + lo] = (_Float16)h1;
        }
        cur ^= 1;
        __syncthreads();                       // lgkm-only drain now
    }

    // fc epilogue: wave w does vocab tiles {2w, 2w+1} below V_=96 (6 tiles)
    half8 aE[4];
    #pragma unroll
    for (int ks = 0; ks < 4; ++ks)
        __builtin_memcpy(&aE[ks], &hs[cur][lo][ks * 32 + g * 8], 16);
    #pragma unroll
    for (int q = 0; q < 2; ++q) {
        const int NT = 2 * w + q;
        if (NT < 6) {
            float bf = b_fc[NT * 16 + lo];
            f32x4 acc = {bf, bf, bf, bf};
            #pragma unroll
            for (int ks = 0; ks < 4; ++ks) {
                union { uint4 u; half8 h; } ub;
                ub.u = wBfcg[(ks * 6 + NT) * 64 + l];
                acc = __builtin_amdgcn_mfma_f32_16x16x32_f16(aE[ks], ub.h, acc, 0, 0, 0);
            }
            #pragma unroll
            for (int j = 0; j < 4; ++j)
                out[(bb * 16 + 4 * g + j) * V_ + NT * 16 + lo] = acc[j];
        }
    }
}

extern "C" void kernel_launch(void* const* d_in, const int* in_sizes, int n_in,
                              void* d_out, int out_size, void* d_ws, size_t ws_size,
                              hipStream_t stream)
{
    const float* x    = (const float*)d_in[0];
    const float* W_ih = (const float*)d_in[1];
    const float* b_ih = (const float*)d_in[2];
    const float* W_hh = (const float*)d_in[3];
    const float* b_hh = (const float*)d_in[4];
    const float* W_fc = (const float*)d_in[5];
    const float* b_fc = (const float*)d_in[6];
    float* out = (float*)d_out;

    char* ws = (char*)d_ws;
    int*      idx  = (int*)ws;                               // 1 MiB
    float*    xwg  = (float*)(ws + (size_t)B_ * T_ * 4);     // 48 KiB
    _Float16* wB   = (_Float16*)((char*)xwg + V_ * H_ * 4);  // 32 KiB
    _Float16* wBfc = (_Float16*)((char*)wB + 16384 * 2);     // 24 KiB

    const int n4 = (B_ * T_ * V_) / 4;
    hipLaunchKernelGGL(onehot_idx_kernel, dim3(2048), dim3(256), 0, stream,
                       (const float4*)x, n4, idx);
    hipLaunchKernelGGL(build_xwg_kernel, dim3((V_ * H_ + 255) / 256), dim3(256),
                       0, stream, W_ih, b_ih, b_hh, xwg);
    hipLaunchKernelGGL(build_wB_kernel, dim3(64), dim3(256), 0, stream, W_hh, wB);
    hipLaunchKernelGGL(build_wBfc_kernel, dim3(48), dim3(256), 0, stream, W_fc, wBfc);
    hipLaunchKernelGGL(rnn_mfma4_kernel, dim3(B_ / 16), dim3(256), 0, stream,
                       (const uint4*)wB, (const uint4*)wBfc, xwg, idx, b_fc, out);
}